// Round 13
// baseline (59.590 us; speedup 1.0000x reference)
//
#include <hip/hip_runtime.h>

#define LD4(p) (*reinterpret_cast<const float4*>(p))
#define HOT 19

__device__ __forceinline__ float dot16(float4 e0, float4 e1, float4 e2, float4 e3,
                                       float4 w0, float4 w1, float4 w2, float4 w3) {
    return e0.x*w0.x + e0.y*w0.y + e0.z*w0.z + e0.w*w0.w
         + e1.x*w1.x + e1.y*w1.y + e1.z*w1.z + e1.w*w1.w
         + e2.x*w2.x + e2.y*w2.y + e2.z*w2.z + e2.w*w2.w
         + e3.x*w3.x + e3.y*w3.y + e3.z*w3.z + e3.w*w3.w;
}

__device__ __forceinline__ float red16(float q) {
    q += __shfl_xor(q, 1, 16);
    q += __shfl_xor(q, 2, 16);
    q += __shfl_xor(q, 4, 16);
    q += __shfl_xor(q, 8, 16);
    return q;   // all 16 lanes of the group hold the group's sum
}

__device__ __forceinline__ float bce_term(float q, float y, float m) {
    return m * (fmaxf(q, 0.0f) - q * y + __logf(1.0f + __expf(-fabsf(q))));
}

// R8 structure + LDS cache of the top-HOT fc rows (highest internal indices =
// root region of the Huffman tree, ~27% of all visits).
__global__ __launch_bounds__(256) void hs_main(
    const float* __restrict__ emb,        // [N, 256]
    const float* __restrict__ fc,         // [C, 256]
    const int*   __restrict__ target,     // [N]
    const int*   __restrict__ path_idx,   // [V, L]
    const float* __restrict__ path_codes, // [V, L]
    const float* __restrict__ path_mask,  // [V, L]
    float2* __restrict__ partials,        // [gridDim.x]
    int N, int L, int C, int hotbase)
{
    // chunk-transposed hot cache: slot[c*HOT*16 + r*16 + li] holds the float4
    // (r, li*4+c) of source row r. Read #c is 256B contiguous per group ->
    // uniform LDS bank utilization.
    __shared__ float4 hotbuf[HOT * 64];   // 19456 B

    const int nhot = C - hotbase;         // <= HOT
    {
        const float4* fsrc = reinterpret_cast<const float4*>(fc) + (size_t)hotbase * 64;
        for (int i = threadIdx.x; i < nhot * 64; i += 256) {
            const int r  = i >> 6;
            const int f  = i & 63;
            const int li = f >> 2, c = f & 3;
            hotbuf[c * (HOT * 16) + r * 16 + li] = fsrc[i];
        }
    }
    __syncthreads();

    const int lane = threadIdx.x & 63;
    const int g    = lane >> 4;           // group 0..3
    const int li   = lane & 15;           // lane in group
    const int wid  = threadIdx.x >> 6;
    const int gwave  = blockIdx.x * (blockDim.x >> 6) + wid;
    const int nwaves = gridDim.x * (blockDim.x >> 6);

    float bce_acc = 0.0f;   // per-lane copy of its group's sum
    float cnt_acc = 0.0f;   // wave-uniform

    for (int row = gwave; row < N; row += nwaves) {
        const float* erow = emb + (size_t)row * 256 + li * 16;
        const float4 e0 = LD4(erow), e1 = LD4(erow + 4),
                     e2 = LD4(erow + 8), e3 = LD4(erow + 12);
        const int t = target[row];

        int pi = 0; float pc = 0.0f, pm = 0.0f;
        if (lane < L) {
            const size_t off = (size_t)t * L + lane;
            pi = path_idx[off];
            pc = path_codes[off];
            pm = path_mask[off];
        }
        const unsigned long long bal = __ballot(pm != 0.0f);
        const int plen = __popcll(bal);   // prefix mask, plen <= 64
        cnt_acc += (float)plen;

        for (int j4 = 0; j4 < plen; j4 += 8) {
            const int i0 = j4 + g;            // <= 63 always
            const int i1 = j4 + 4 + g;        // <= 63 always
            const int n0 = __shfl(pi, i0, 64);
            const int n1 = __shfl(pi, i1, 64);

            float4 a0, a1, a2, a3, b0, b1, b2, b3;
            if (n0 >= hotbase) {
                const int r = n0 - hotbase;
                a0 = hotbuf[0*(HOT*16) + r*16 + li];
                a1 = hotbuf[1*(HOT*16) + r*16 + li];
                a2 = hotbuf[2*(HOT*16) + r*16 + li];
                a3 = hotbuf[3*(HOT*16) + r*16 + li];
            } else {
                const float* p0 = fc + ((size_t)n0 << 8) + li * 16;
                a0 = LD4(p0); a1 = LD4(p0 + 4); a2 = LD4(p0 + 8); a3 = LD4(p0 + 12);
            }
            if (n1 >= hotbase) {
                const int r = n1 - hotbase;
                b0 = hotbuf[0*(HOT*16) + r*16 + li];
                b1 = hotbuf[1*(HOT*16) + r*16 + li];
                b2 = hotbuf[2*(HOT*16) + r*16 + li];
                b3 = hotbuf[3*(HOT*16) + r*16 + li];
            } else {
                const float* p1 = fc + ((size_t)n1 << 8) + li * 16;
                b0 = LD4(p1); b1 = LD4(p1 + 4); b2 = LD4(p1 + 8); b3 = LD4(p1 + 12);
            }

            const float y0 = __shfl(pc, i0, 64);
            const float y1 = __shfl(pc, i1, 64);
            const float m0 = (i0 < plen) ? 1.0f : 0.0f;
            const float m1 = (i1 < plen) ? 1.0f : 0.0f;

            float q0 = dot16(e0, e1, e2, e3, a0, a1, a2, a3);
            float q1 = dot16(e0, e1, e2, e3, b0, b1, b2, b3);
            q0 = red16(q0);
            q1 = red16(q1);

            bce_acc += bce_term(q0, y0, m0);
            bce_acc += bce_term(q1, y1, m1);
        }
    }

    // sum the 4 groups (each lane holds its group's total)
    bce_acc += __shfl_xor(bce_acc, 16, 64);
    bce_acc += __shfl_xor(bce_acc, 32, 64);

    __shared__ float s_b[4], s_c[4];
    if (lane == 0) { s_b[wid] = bce_acc; s_c[wid] = cnt_acc; }
    __syncthreads();
    if (threadIdx.x == 0) {
        const int nw = blockDim.x >> 6;
        float b = 0.0f, c = 0.0f;
        for (int i = 0; i < nw; ++i) { b += s_b[i]; c += s_c[i]; }
        partials[blockIdx.x] = make_float2(b, c);
    }
}

__global__ __launch_bounds__(256) void hs_fin(
    const float2* __restrict__ partials, int nparts, float* __restrict__ out)
{
    double b = 0.0, c = 0.0;
    for (int i = threadIdx.x; i < nparts; i += blockDim.x) {
        const float2 p = partials[i];
        b += (double)p.x;
        c += (double)p.y;
    }
    __shared__ double sb[256], sc[256];
    sb[threadIdx.x] = b; sc[threadIdx.x] = c;
    __syncthreads();
    for (int s = 128; s > 0; s >>= 1) {
        if (threadIdx.x < s) {
            sb[threadIdx.x] += sb[threadIdx.x + s];
            sc[threadIdx.x] += sc[threadIdx.x + s];
        }
        __syncthreads();
    }
    if (threadIdx.x == 0) out[0] = (float)(sb[0] / sc[0]);
}

extern "C" void kernel_launch(void* const* d_in, const int* in_sizes, int n_in,
                              void* d_out, int out_size, void* d_ws, size_t ws_size,
                              hipStream_t stream) {
    const float* emb        = (const float*)d_in[0];
    const float* fc         = (const float*)d_in[1];
    const int*   target     = (const int*)d_in[2];
    const int*   path_idx   = (const int*)d_in[3];
    const float* path_codes = (const float*)d_in[4];
    const float* path_mask  = (const float*)d_in[5];

    const int N = in_sizes[2];
    const int C = in_sizes[1] / 256;       // fc rows (V-1)
    const int V = C + 1;
    const int L = in_sizes[3] / V;

    float2* partials = (float2*)d_ws;
    float*  out      = (float*)d_out;

    const int hotbase = (C > HOT) ? (C - HOT) : 0;

    const int block = 256;                 // 4 waves/block, 1 row per wave
    int nblocks = (N + 3) / 4;             // 2048 blocks -> 8192 waves
    if (nblocks < 1) nblocks = 1;
    if ((size_t)nblocks * sizeof(float2) > ws_size)
        nblocks = (int)(ws_size / sizeof(float2));

    hs_main<<<nblocks, block, 0, stream>>>(emb, fc, target, path_idx, path_codes,
                                           path_mask, partials, N, L, C, hotbase);
    hs_fin<<<1, block, 0, stream>>>(partials, nblocks, out);
}

// Round 14
// 30.946 us; speedup vs baseline: 1.9256x; 1.9256x over previous
//
#include <hip/hip_runtime.h>

#define LD4(p) (*reinterpret_cast<const float4*>(p))

__device__ __forceinline__ float dot16(float4 e0, float4 e1, float4 e2, float4 e3,
                                       float4 w0, float4 w1, float4 w2, float4 w3) {
    return e0.x*w0.x + e0.y*w0.y + e0.z*w0.z + e0.w*w0.w
         + e1.x*w1.x + e1.y*w1.y + e1.z*w1.z + e1.w*w1.w
         + e2.x*w2.x + e2.y*w2.y + e2.z*w2.z + e2.w*w2.w
         + e3.x*w3.x + e3.y*w3.y + e3.z*w3.z + e3.w*w3.w;
}

__device__ __forceinline__ float red16(float q) {
    q += __shfl_xor(q, 1, 16);
    q += __shfl_xor(q, 2, 16);
    q += __shfl_xor(q, 4, 16);
    q += __shfl_xor(q, 8, 16);
    return q;   // all 16 lanes of the group hold the group's sum
}

__device__ __forceinline__ float bce_term(float q, float y, float m) {
    return m * (fmaxf(q, 0.0f) - q * y + __logf(1.0f + __expf(-fabsf(q))));
}

// R8 inner structure, but each row is split across 2 waves (half the path
// each): 16384 waves = 4096 blocks = 2x CU capacity. Blocks are short, so
// the HW dispatcher replaces retiring blocks mid-kernel -> no drain tail,
// no atomics.
__global__ __launch_bounds__(256) void hs_main(
    const float* __restrict__ emb,        // [N, 256]
    const float* __restrict__ fc,         // [C, 256]
    const int*   __restrict__ target,     // [N]
    const int*   __restrict__ path_idx,   // [V, L]
    const float* __restrict__ path_codes, // [V, L]
    const float* __restrict__ path_mask,  // [V, L]
    float2* __restrict__ partials,        // [gridDim.x]
    int N, int L)
{
    const int lane = threadIdx.x & 63;
    const int g    = lane >> 4;           // group 0..3
    const int li   = lane & 15;           // lane in group
    const int wid  = threadIdx.x >> 6;
    const int gwave = blockIdx.x * (blockDim.x >> 6) + wid;
    const int row  = gwave >> 1;          // 2 waves per row
    const int half = gwave & 1;

    float bce_acc = 0.0f;   // per-lane copy of its group's sum
    float cnt_acc = 0.0f;

    if (row < N) {
        const float* erow = emb + (size_t)row * 256 + li * 16;
        const float4 e0 = LD4(erow), e1 = LD4(erow + 4),
                     e2 = LD4(erow + 8), e3 = LD4(erow + 12);
        const int t = target[row];

        // path metadata: lane l holds entry l (coalesced); padded entries 0
        int pi = 0; float pc = 0.0f, pm = 0.0f;
        if (lane < L) {
            const size_t off = (size_t)t * L + lane;
            pi = path_idx[off];
            pc = path_codes[off];
            pm = path_mask[off];
        }
        const unsigned long long bal = __ballot(pm != 0.0f);
        const int plen = __popcll(bal);       // prefix mask, plen <= 64
        if (half == 0) cnt_acc = (float)plen; // count once per row

        const int hl    = (plen + 1) >> 1;    // half length (ceil)
        const int start = half * hl;
        const int end   = (half == 0) ? hl : plen;

        for (int j = start; j < end; j += 8) {
            const int i0 = j + g;             // <= 63 (see half-split bounds)
            const int i1 = j + 4 + g;         // <= 63
            const int n0 = __shfl(pi, i0, 64);
            const int n1 = __shfl(pi, i1, 64);
            const float* p0 = fc + ((size_t)n0 << 8) + li * 16;
            const float* p1 = fc + ((size_t)n1 << 8) + li * 16;
            const float4 a0 = LD4(p0), a1 = LD4(p0 + 4),
                         a2 = LD4(p0 + 8), a3 = LD4(p0 + 12);
            const float4 b0 = LD4(p1), b1 = LD4(p1 + 4),
                         b2 = LD4(p1 + 8), b3 = LD4(p1 + 12);
            const float y0 = __shfl(pc, i0, 64);
            const float y1 = __shfl(pc, i1, 64);
            const float m0 = (i0 < end) ? 1.0f : 0.0f;
            const float m1 = (i1 < end) ? 1.0f : 0.0f;

            float q0 = dot16(e0, e1, e2, e3, a0, a1, a2, a3);
            float q1 = dot16(e0, e1, e2, e3, b0, b1, b2, b3);
            q0 = red16(q0);
            q1 = red16(q1);

            bce_acc += bce_term(q0, y0, m0);
            bce_acc += bce_term(q1, y1, m1);
        }
    }

    // sum the 4 groups (each lane holds its group's total)
    bce_acc += __shfl_xor(bce_acc, 16, 64);
    bce_acc += __shfl_xor(bce_acc, 32, 64);

    __shared__ float s_b[4], s_c[4];
    if (lane == 0) { s_b[wid] = bce_acc; s_c[wid] = cnt_acc; }
    __syncthreads();
    if (threadIdx.x == 0) {
        const int nw = blockDim.x >> 6;
        float b = 0.0f, c = 0.0f;
        for (int i = 0; i < nw; ++i) { b += s_b[i]; c += s_c[i]; }
        partials[blockIdx.x] = make_float2(b, c);
    }
}

__global__ __launch_bounds__(256) void hs_fin(
    const float2* __restrict__ partials, int nparts, float* __restrict__ out)
{
    double b = 0.0, c = 0.0;
    for (int i = threadIdx.x; i < nparts; i += blockDim.x) {
        const float2 p = partials[i];
        b += (double)p.x;
        c += (double)p.y;
    }
    __shared__ double sb[256], sc[256];
    sb[threadIdx.x] = b; sc[threadIdx.x] = c;
    __syncthreads();
    for (int s = 128; s > 0; s >>= 1) {
        if (threadIdx.x < s) {
            sb[threadIdx.x] += sb[threadIdx.x + s];
            sc[threadIdx.x] += sc[threadIdx.x + s];
        }
        __syncthreads();
    }
    if (threadIdx.x == 0) out[0] = (float)(sb[0] / sc[0]);
}

extern "C" void kernel_launch(void* const* d_in, const int* in_sizes, int n_in,
                              void* d_out, int out_size, void* d_ws, size_t ws_size,
                              hipStream_t stream) {
    const float* emb        = (const float*)d_in[0];
    const float* fc         = (const float*)d_in[1];
    const int*   target     = (const int*)d_in[2];
    const int*   path_idx   = (const int*)d_in[3];
    const float* path_codes = (const float*)d_in[4];
    const float* path_mask  = (const float*)d_in[5];

    const int N = in_sizes[2];
    const int V = in_sizes[1] / 256 + 1;
    const int L = in_sizes[3] / V;

    float2* partials = (float2*)d_ws;
    float*  out      = (float*)d_out;

    const int block = 256;                 // 4 waves/block, 2 waves per row
    int nblocks = (N * 2 + 3) / 4;         // 4096 blocks = 2x CU capacity
    if (nblocks < 1) nblocks = 1;
    if ((size_t)nblocks * sizeof(float2) > ws_size)
        nblocks = (int)(ws_size / sizeof(float2));

    hs_main<<<nblocks, block, 0, stream>>>(emb, fc, target, path_idx, path_codes,
                                           path_mask, partials, N, L);
    hs_fin<<<1, block, 0, stream>>>(partials, nblocks, out);
}

// Round 15
// 24.268 us; speedup vs baseline: 2.4555x; 1.2752x over previous
//
#include <hip/hip_runtime.h>

#define LD4(p) (*reinterpret_cast<const float4*>(p))

__device__ __forceinline__ float dot16(float4 e0, float4 e1, float4 e2, float4 e3,
                                       float4 w0, float4 w1, float4 w2, float4 w3) {
    return e0.x*w0.x + e0.y*w0.y + e0.z*w0.z + e0.w*w0.w
         + e1.x*w1.x + e1.y*w1.y + e1.z*w1.z + e1.w*w1.w
         + e2.x*w2.x + e2.y*w2.y + e2.z*w2.z + e2.w*w2.w
         + e3.x*w3.x + e3.y*w3.y + e3.z*w3.z + e3.w*w3.w;
}

__device__ __forceinline__ float red16(float q) {
    q += __shfl_xor(q, 1, 16);
    q += __shfl_xor(q, 2, 16);
    q += __shfl_xor(q, 4, 16);
    q += __shfl_xor(q, 8, 16);
    return q;   // all 16 lanes of the group hold the group's sum
}

__device__ __forceinline__ float bce_term(float q, float y, float m) {
    return m * (fmaxf(q, 0.0f) - q * y + __logf(1.0f + __expf(-fabsf(q))));
}

// R8 structure (one wave per row, 4 groups of 16 lanes split the path) with
// micro-trims: codes via one per-row ballot instead of per-iter shuffles,
// 32-bit byte-offset addressing for the fc gathers.
__global__ __launch_bounds__(256) void hs_main(
    const float* __restrict__ emb,        // [N, 256]
    const float* __restrict__ fc,         // [C, 256]
    const int*   __restrict__ target,     // [N]
    const int*   __restrict__ path_idx,   // [V, L]
    const float* __restrict__ path_codes, // [V, L]
    const float* __restrict__ path_mask,  // [V, L]
    float2* __restrict__ partials,        // [gridDim.x]
    int N, int L)
{
    const int lane = threadIdx.x & 63;
    const int g    = lane >> 4;           // group 0..3
    const int li   = lane & 15;           // lane in group
    const int wid  = threadIdx.x >> 6;
    const int gwave  = blockIdx.x * (blockDim.x >> 6) + wid;
    const int nwaves = gridDim.x * (blockDim.x >> 6);

    float bce_acc = 0.0f;   // per-lane copy of its group's sum
    float cnt_acc = 0.0f;   // wave-uniform

    const char* fcb = (const char*)fc;
    const unsigned libase = (unsigned)(li << 6);   // byte offset of lane's 16 floats

    for (int row = gwave; row < N; row += nwaves) {
        const float* erow = emb + (size_t)row * 256 + li * 16;
        const float4 e0 = LD4(erow), e1 = LD4(erow + 4),
                     e2 = LD4(erow + 8), e3 = LD4(erow + 12);
        const int t = target[row];

        // path metadata: lane l holds entry l (coalesced); padded entries 0
        int pi = 0; float pc = 0.0f, pm = 0.0f;
        if (lane < L) {
            const size_t off = (size_t)t * L + lane;
            pi = path_idx[off];
            pc = path_codes[off];
            pm = path_mask[off];
        }
        const unsigned long long cmask = __ballot(pc != 0.0f);  // per-row code bits
        const unsigned long long bal   = __ballot(pm != 0.0f);
        const int plen = __popcll(bal);   // prefix mask, plen <= 64
        cnt_acc += (float)plen;

        for (int j4 = 0; j4 < plen; j4 += 8) {
            const int i0 = j4 + g;            // <= 63 always
            const int i1 = j4 + 4 + g;        // <= 63 always
            const int n0 = __shfl(pi, i0, 64);
            const int n1 = __shfl(pi, i1, 64);
            // 32-bit byte offsets (n < 2^17, <<10 fits 27 bits)
            const float4* p0 = (const float4*)(fcb + (((unsigned)n0 << 10) | libase));
            const float4* p1 = (const float4*)(fcb + (((unsigned)n1 << 10) | libase));
            const float4 a0 = p0[0], a1 = p0[1], a2 = p0[2], a3 = p0[3];
            const float4 b0 = p1[0], b1 = p1[1], b2 = p1[2], b3 = p1[3];
            // codes from the ballot mask: no LDS-pipe op
            const float y0 = (float)((cmask >> i0) & 1ull);
            const float y1 = (float)((cmask >> i1) & 1ull);
            const float m0 = (i0 < plen) ? 1.0f : 0.0f;
            const float m1 = (i1 < plen) ? 1.0f : 0.0f;

            float q0 = dot16(e0, e1, e2, e3, a0, a1, a2, a3);
            float q1 = dot16(e0, e1, e2, e3, b0, b1, b2, b3);
            q0 = red16(q0);
            q1 = red16(q1);

            bce_acc += bce_term(q0, y0, m0);
            bce_acc += bce_term(q1, y1, m1);
        }
    }

    // sum the 4 groups (each lane holds its group's total)
    bce_acc += __shfl_xor(bce_acc, 16, 64);
    bce_acc += __shfl_xor(bce_acc, 32, 64);

    __shared__ float s_b[4], s_c[4];
    if (lane == 0) { s_b[wid] = bce_acc; s_c[wid] = cnt_acc; }
    __syncthreads();
    if (threadIdx.x == 0) {
        const int nw = blockDim.x >> 6;
        float b = 0.0f, c = 0.0f;
        for (int i = 0; i < nw; ++i) { b += s_b[i]; c += s_c[i]; }
        partials[blockIdx.x] = make_float2(b, c);
    }
}

__global__ __launch_bounds__(256) void hs_fin(
    const float2* __restrict__ partials, int nparts, float* __restrict__ out)
{
    double b = 0.0, c = 0.0;
    for (int i = threadIdx.x; i < nparts; i += blockDim.x) {
        const float2 p = partials[i];
        b += (double)p.x;
        c += (double)p.y;
    }
    __shared__ double sb[256], sc[256];
    sb[threadIdx.x] = b; sc[threadIdx.x] = c;
    __syncthreads();
    for (int s = 128; s > 0; s >>= 1) {
        if (threadIdx.x < s) {
            sb[threadIdx.x] += sb[threadIdx.x + s];
            sc[threadIdx.x] += sc[threadIdx.x + s];
        }
        __syncthreads();
    }
    if (threadIdx.x == 0) out[0] = (float)(sb[0] / sc[0]);
}

extern "C" void kernel_launch(void* const* d_in, const int* in_sizes, int n_in,
                              void* d_out, int out_size, void* d_ws, size_t ws_size,
                              hipStream_t stream) {
    const float* emb        = (const float*)d_in[0];
    const float* fc         = (const float*)d_in[1];
    const int*   target     = (const int*)d_in[2];
    const int*   path_idx   = (const int*)d_in[3];
    const float* path_codes = (const float*)d_in[4];
    const float* path_mask  = (const float*)d_in[5];

    const int N = in_sizes[2];
    const int V = in_sizes[1] / 256 + 1;
    const int L = in_sizes[3] / V;

    float2* partials = (float2*)d_ws;
    float*  out      = (float*)d_out;

    const int block = 256;                 // 4 waves/block, 1 row per wave
    int nblocks = (N + 3) / 4;             // 2048 blocks -> 8192 waves
    if (nblocks < 1) nblocks = 1;
    if ((size_t)nblocks * sizeof(float2) > ws_size)
        nblocks = (int)(ws_size / sizeof(float2));

    hs_main<<<nblocks, block, 0, stream>>>(emb, fc, target, path_idx, path_codes,
                                           path_mask, partials, N, L);
    hs_fin<<<1, block, 0, stream>>>(partials, nblocks, out);
}